// Round 18
// baseline (933.317 us; speedup 1.0000x reference)
//
#include <hip/hip_runtime.h>
#include <math.h>

static __device__ __forceinline__ float sigf(float v) { return 1.0f / (1.0f + expf(-v)); }

using s8v = __attribute__((ext_vector_type(8))) short;   // 8 bf16 (4 VGPR)
using f4v = __attribute__((ext_vector_type(4))) float;   // MFMA acc

static __device__ __forceinline__ void splitf(float f, unsigned short& h, unsigned short& l) {
  unsigned u = __float_as_uint(f);
  unsigned short hb = (unsigned short)((u + 0x7FFFu + ((u >> 16) & 1u)) >> 16);
  float hf = __uint_as_float(((unsigned)hb) << 16);
  float lf = f - hf;
  unsigned ul = __float_as_uint(lf);
  unsigned short lb = (unsigned short)((ul + 0x7FFFu + ((ul >> 16) & 1u)) >> 16);
  h = hb; l = lb;
}

// Fast float4 -> packed bf16 hi/lo via HW v_cvt_pk_bf16_f32 (RTNE).
static __device__ __forceinline__ void splitf4(float4 a, uint2& hOut, uint2& lOut) {
  unsigned hxy, hzw;
  asm("v_cvt_pk_bf16_f32 %0, %1, %2" : "=v"(hxy) : "v"(a.x), "v"(a.y));
  asm("v_cvt_pk_bf16_f32 %0, %1, %2" : "=v"(hzw) : "v"(a.z), "v"(a.w));
  float hx = __uint_as_float(hxy << 16);
  float hy = __uint_as_float(hxy & 0xFFFF0000u);
  float hz = __uint_as_float(hzw << 16);
  float hw = __uint_as_float(hzw & 0xFFFF0000u);
  unsigned lxy, lzw;
  asm("v_cvt_pk_bf16_f32 %0, %1, %2" : "=v"(lxy) : "v"(a.x - hx), "v"(a.y - hy));
  asm("v_cvt_pk_bf16_f32 %0, %1, %2" : "=v"(lzw) : "v"(a.z - hz), "v"(a.w - hw));
  hOut.x = hxy; hOut.y = hzw;
  lOut.x = lxy; lOut.y = lzw;
}

// ---------------------------------------------------------------------------
// Fused weight split: 4 segments (en1, en2, de1, de2) in one launch.
// ---------------------------------------------------------------------------
struct WsplitArgs {
  const float* W[4];
  unsigned short* WH[4];
  unsigned short* WL[4];
};
__global__ __launch_bounds__(256) void wsplit4(WsplitArgs a)
{
  int blk = blockIdx.x;
  int seg, base;
  if (blk < 4096)      { seg = 0; base = blk; }
  else if (blk < 4352) { seg = 1; base = blk - 4096; }
  else if (blk < 4608) { seg = 2; base = blk - 4352; }
  else                 { seg = 3; base = blk - 4608; }
  int i = base * 256 + threadIdx.x;
  float4 v = ((const float4*)a.W[seg])[i];
  ushort4 h, l;
  splitf(v.x, h.x, l.x); splitf(v.y, h.y, l.y);
  splitf(v.z, h.z, l.z); splitf(v.w, h.w, l.w);
  ((ushort4*)a.WH[seg])[i] = h;
  ((ushort4*)a.WL[seg])[i] = l;
}

// ---------------------------------------------------------------------------
// Cell weight prep: gate-interleaved concat pack + bf16 split.
// WcatH/L[l][(j*4+s)*512 + k]     = split(whh[s*256+j][k])   (k<256)
// WcatH/L[l][(j*4+s)*512 + 256+k] = split(wih[s*256+j][k])
// bP[l][j*4+s] = bih[s*256+j] + bhh[s*256+j].  grid (256 j, 6 l), 256 thr (k).
// ---------------------------------------------------------------------------
struct PrepArgs {
  const float* wih[6];
  const float* whh[6];
  const float* bih[6];
  const float* bhh[6];
  unsigned short* WcatH;  // [6][1024*512]
  unsigned short* WcatL;
  float* bP;              // [6][1024]
};
__global__ __launch_bounds__(256) void prep_cat6(PrepArgs a)
{
  const int l = blockIdx.y;
  const int j = blockIdx.x, k = threadIdx.x;
  unsigned short* WH = a.WcatH + (size_t)l * 524288;
  unsigned short* WL = a.WcatL + (size_t)l * 524288;
#pragma unroll
  for (int s = 0; s < 4; ++s) {
    unsigned short h, lo;
    float wh = a.whh[l][(s * 256 + j) * 256 + k];
    splitf(wh, h, lo);
    WH[(size_t)(j * 4 + s) * 512 + k] = h;
    WL[(size_t)(j * 4 + s) * 512 + k] = lo;
    float wi = a.wih[l][(s * 256 + j) * 256 + k];
    splitf(wi, h, lo);
    WH[(size_t)(j * 4 + s) * 512 + 256 + k] = h;
    WL[(size_t)(j * 4 + s) * 512 + 256 + k] = lo;
  }
  if (k < 4)
    a.bP[l * 1024 + j * 4 + k] = a.bih[l][k * 256 + j] + a.bhh[l][k * 256 + j];
}

// ---------------------------------------------------------------------------
// MFMA GEMM, A fp32 split on the fly (HW cvt_pk), W pre-split. (fc_en1)
// Tile 128(M) x 64(N), BK=32, 4 waves.
// ---------------------------------------------------------------------------
template <int OSPLIT>
__global__ __launch_bounds__(256) void gemm_sf(
    const float* __restrict__ A,
    const unsigned short* __restrict__ WH, const unsigned short* __restrict__ WL,
    const float* __restrict__ bias, float* __restrict__ C,
    unsigned short* __restrict__ OH, unsigned short* __restrict__ OL,
    int M, int N, int K, int act)
{
  __shared__ unsigned short AsH[128 * 40];
  __shared__ unsigned short AsL[128 * 40];
  __shared__ unsigned short WsH[64 * 40];
  __shared__ unsigned short WsL[64 * 40];

  const int t = threadIdx.x;
  const int w = t >> 6, lane = t & 63;
  const int lrow = lane & 15, lk = (lane >> 4) * 8;
  const int m0 = blockIdx.x * 128, n0 = blockIdx.y * 64;

  f4v acc[2][4];
#pragma unroll
  for (int i = 0; i < 2; ++i)
#pragma unroll
    for (int j = 0; j < 4; ++j) acc[i][j] = (f4v){0.f, 0.f, 0.f, 0.f};

  for (int k0 = 0; k0 < K; k0 += 32) {
#pragma unroll
    for (int i = 0; i < 4; ++i) {
      int v = i * 256 + t;
      int row = v >> 3, kq = (v & 7) << 2;
      float4 a = *(const float4*)(A + (size_t)(m0 + row) * K + k0 + kq);
      uint2 h2, l2;
      splitf4(a, h2, l2);
      *(uint2*)&AsH[row * 40 + kq] = h2;
      *(uint2*)&AsL[row * 40 + kq] = l2;
    }
    {
      int row = t >> 2, q = (t & 3) * 8;
      *(s8v*)&WsH[row * 40 + q] = *(const s8v*)(WH + (size_t)(n0 + row) * K + k0 + q);
      *(s8v*)&WsL[row * 40 + q] = *(const s8v*)(WL + (size_t)(n0 + row) * K + k0 + q);
    }
    __syncthreads();

    s8v aH[2], aL[2], bH[4], bL[4];
#pragma unroll
    for (int mt = 0; mt < 2; ++mt) {
      int r = (w * 32 + mt * 16 + lrow) * 40 + lk;
      aH[mt] = *(const s8v*)&AsH[r];
      aL[mt] = *(const s8v*)&AsL[r];
    }
#pragma unroll
    for (int nt = 0; nt < 4; ++nt) {
      int r = (nt * 16 + lrow) * 40 + lk;
      bH[nt] = *(const s8v*)&WsH[r];
      bL[nt] = *(const s8v*)&WsL[r];
    }
#pragma unroll
    for (int mt = 0; mt < 2; ++mt)
#pragma unroll
      for (int nt = 0; nt < 4; ++nt) {
        acc[mt][nt] = __builtin_amdgcn_mfma_f32_16x16x32_bf16(aH[mt], bH[nt], acc[mt][nt], 0, 0, 0);
        acc[mt][nt] = __builtin_amdgcn_mfma_f32_16x16x32_bf16(aH[mt], bL[nt], acc[mt][nt], 0, 0, 0);
        acc[mt][nt] = __builtin_amdgcn_mfma_f32_16x16x32_bf16(aL[mt], bH[nt], acc[mt][nt], 0, 0, 0);
      }
    __syncthreads();
  }

#pragma unroll
  for (int mt = 0; mt < 2; ++mt)
#pragma unroll
    for (int nt = 0; nt < 4; ++nt) {
      int gcol = n0 + nt * 16 + lrow;
      float bv = bias[gcol];
#pragma unroll
      for (int r = 0; r < 4; ++r) {
        int grow = m0 + w * 32 + mt * 16 + (lane >> 4) * 4 + r;
        float v = acc[mt][nt][r] + bv;
        if (act == 1) v = fmaxf(v, 0.f);
        else if (act == 2) v = tanhf(v);
        if (OSPLIT) {
          unsigned short h, l;
          splitf(v, h, l);
          OH[(size_t)grow * N + gcol] = h;
          OL[(size_t)grow * N + gcol] = l;
        } else {
          C[(size_t)grow * N + gcol] = v;
        }
      }
    }
}

// ---------------------------------------------------------------------------
// MFMA GEMM, A AND W pre-split bf16. Tile 128x64, BK=32.
// ---------------------------------------------------------------------------
template <int OSPLIT>
__global__ __launch_bounds__(256) void gemm_bb(
    const unsigned short* __restrict__ AH, const unsigned short* __restrict__ AL,
    const unsigned short* __restrict__ WH, const unsigned short* __restrict__ WL,
    const float* __restrict__ bias, float* __restrict__ C,
    unsigned short* __restrict__ OH, unsigned short* __restrict__ OL,
    int M, int N, int K, int act)
{
  __shared__ unsigned short AsH[128 * 40];
  __shared__ unsigned short AsL[128 * 40];
  __shared__ unsigned short WsH[64 * 40];
  __shared__ unsigned short WsL[64 * 40];

  const int t = threadIdx.x;
  const int w = t >> 6, lane = t & 63;
  const int lrow = lane & 15, lk = (lane >> 4) * 8;
  const int m0 = blockIdx.x * 128, n0 = blockIdx.y * 64;

  f4v acc[2][4];
#pragma unroll
  for (int i = 0; i < 2; ++i)
#pragma unroll
    for (int j = 0; j < 4; ++j) acc[i][j] = (f4v){0.f, 0.f, 0.f, 0.f};

  for (int k0 = 0; k0 < K; k0 += 32) {
#pragma unroll
    for (int i = 0; i < 2; ++i) {
      int v = i * 256 + t;
      int row = v >> 2, q = (v & 3) * 8;
      *(s8v*)&AsH[row * 40 + q] = *(const s8v*)(AH + (size_t)(m0 + row) * K + k0 + q);
      *(s8v*)&AsL[row * 40 + q] = *(const s8v*)(AL + (size_t)(m0 + row) * K + k0 + q);
    }
    {
      int row = t >> 2, q = (t & 3) * 8;
      *(s8v*)&WsH[row * 40 + q] = *(const s8v*)(WH + (size_t)(n0 + row) * K + k0 + q);
      *(s8v*)&WsL[row * 40 + q] = *(const s8v*)(WL + (size_t)(n0 + row) * K + k0 + q);
    }
    __syncthreads();

    s8v aH[2], aL[2], bH[4], bL[4];
#pragma unroll
    for (int mt = 0; mt < 2; ++mt) {
      int r = (w * 32 + mt * 16 + lrow) * 40 + lk;
      aH[mt] = *(const s8v*)&AsH[r];
      aL[mt] = *(const s8v*)&AsL[r];
    }
#pragma unroll
    for (int nt = 0; nt < 4; ++nt) {
      int r = (nt * 16 + lrow) * 40 + lk;
      bH[nt] = *(const s8v*)&WsH[r];
      bL[nt] = *(const s8v*)&WsL[r];
    }
#pragma unroll
    for (int mt = 0; mt < 2; ++mt)
#pragma unroll
      for (int nt = 0; nt < 4; ++nt) {
        acc[mt][nt] = __builtin_amdgcn_mfma_f32_16x16x32_bf16(aH[mt], bH[nt], acc[mt][nt], 0, 0, 0);
        acc[mt][nt] = __builtin_amdgcn_mfma_f32_16x16x32_bf16(aH[mt], bL[nt], acc[mt][nt], 0, 0, 0);
        acc[mt][nt] = __builtin_amdgcn_mfma_f32_16x16x32_bf16(aL[mt], bH[nt], acc[mt][nt], 0, 0, 0);
      }
    __syncthreads();
  }

#pragma unroll
  for (int mt = 0; mt < 2; ++mt)
#pragma unroll
    for (int nt = 0; nt < 4; ++nt) {
      int gcol = n0 + nt * 16 + lrow;
      float bv = bias[gcol];
#pragma unroll
      for (int r = 0; r < 4; ++r) {
        int grow = m0 + w * 32 + mt * 16 + (lane >> 4) * 4 + r;
        float v = acc[mt][nt][r] + bv;
        if (act == 1) v = fmaxf(v, 0.f);
        else if (act == 2) v = tanhf(v);
        if (OSPLIT) {
          unsigned short h, l;
          splitf(v, h, l);
          OH[(size_t)grow * N + gcol] = h;
          OL[(size_t)grow * N + gcol] = l;
        } else {
          C[(size_t)grow * N + gcol] = v;
        }
      }
    }
}

// ---------------------------------------------------------------------------
// MFMA LSTM cell: gatesT[1024 g][256 b] = Wcat[1024][512] @ hx[b][k]^T.
// Gate rows g = j*4+s (gate-interleaved) -> each lane's 4-reg C fragment is
// (i,f,g,o) of one (j,b); nonlinearity fused in epilogue. h written bf16-split
// in [b][j] layout via LDS transpose (= next cell's B operand).
// Slot = blockIdx>>5 (up to 3 pipelined cells); 32 blocks/slot (8 m x 4 n).
// K = 512 (h then x) or 256 (no x, de1).
// ---------------------------------------------------------------------------
struct CSlot {
  const unsigned short* wH;  // [1024][512]
  const unsigned short* wL;
  const float* bias;         // [1024] (j*4+s)
  const unsigned short* xH;  // [256][256] (b,k) or null
  const unsigned short* xL;
  const unsigned short* hH;  // [256][256] (b,k)
  const unsigned short* hL;
  float* c;                  // [256][256] (j,b) in-place
  unsigned short* oH;        // h out [256 b][256 j]
  unsigned short* oL;
  unsigned short* h3H;       // optional extra copy (H3), or null
  unsigned short* h3L;
  int h3off;                 // H3 row offset (step*256)
  int K;                     // 512 or 256
};
struct CArgs { CSlot s[3]; };

__global__ __launch_bounds__(256) void cell_mfma(CArgs args)
{
  __shared__ unsigned short AsH[128 * 40];
  __shared__ unsigned short AsL[128 * 40];
  __shared__ unsigned short WsH[64 * 40];
  __shared__ unsigned short WsL[64 * 40];
  __shared__ unsigned short tH[64 * 34];
  __shared__ unsigned short tL[64 * 34];

  const CSlot S = args.s[blockIdx.x >> 5];
  const int inner = blockIdx.x & 31;
  const int m0 = (inner >> 2) * 128, n0 = (inner & 3) * 64;
  const int t = threadIdx.x;
  const int w = t >> 6, lane = t & 63;
  const int lrow = lane & 15, lk = (lane >> 4) * 8;

  f4v acc[2][4];
#pragma unroll
  for (int i = 0; i < 2; ++i)
#pragma unroll
    for (int j = 0; j < 4; ++j) acc[i][j] = (f4v){0.f, 0.f, 0.f, 0.f};

  for (int k0 = 0; k0 < S.K; k0 += 32) {
#pragma unroll
    for (int i = 0; i < 2; ++i) {
      int v = i * 256 + t;
      int row = v >> 2, q = (v & 3) * 8;
      *(s8v*)&AsH[row * 40 + q] = *(const s8v*)(S.wH + (size_t)(m0 + row) * 512 + k0 + q);
      *(s8v*)&AsL[row * 40 + q] = *(const s8v*)(S.wL + (size_t)(m0 + row) * 512 + k0 + q);
    }
    {
      const unsigned short* bh = (k0 < 256) ? (S.hH + k0) : (S.xH + (k0 - 256));
      const unsigned short* bl = (k0 < 256) ? (S.hL + k0) : (S.xL + (k0 - 256));
      int row = t >> 2, q = (t & 3) * 8;
      *(s8v*)&WsH[row * 40 + q] = *(const s8v*)(bh + (size_t)(n0 + row) * 256 + q);
      *(s8v*)&WsL[row * 40 + q] = *(const s8v*)(bl + (size_t)(n0 + row) * 256 + q);
    }
    __syncthreads();

    s8v aH[2], aL[2], bH[4], bL[4];
#pragma unroll
    for (int mt = 0; mt < 2; ++mt) {
      int r = (w * 32 + mt * 16 + lrow) * 40 + lk;
      aH[mt] = *(const s8v*)&AsH[r];
      aL[mt] = *(const s8v*)&AsL[r];
    }
#pragma unroll
    for (int nt = 0; nt < 4; ++nt) {
      int r = (nt * 16 + lrow) * 40 + lk;
      bH[nt] = *(const s8v*)&WsH[r];
      bL[nt] = *(const s8v*)&WsL[r];
    }
#pragma unroll
    for (int mt = 0; mt < 2; ++mt)
#pragma unroll
      for (int nt = 0; nt < 4; ++nt) {
        acc[mt][nt] = __builtin_amdgcn_mfma_f32_16x16x32_bf16(aH[mt], bH[nt], acc[mt][nt], 0, 0, 0);
        acc[mt][nt] = __builtin_amdgcn_mfma_f32_16x16x32_bf16(aH[mt], bL[nt], acc[mt][nt], 0, 0, 0);
        acc[mt][nt] = __builtin_amdgcn_mfma_f32_16x16x32_bf16(aL[mt], bH[nt], acc[mt][nt], 0, 0, 0);
      }
    __syncthreads();
  }

  // ---- fused LSTM epilogue: per lane, acc[mt][nt][0..3] = (i,f,g,o) of (j,b)
#pragma unroll
  for (int mt = 0; mt < 2; ++mt)
#pragma unroll
    for (int nt = 0; nt < 4; ++nt) {
      const int gbase = m0 + w * 32 + mt * 16 + (lane >> 4) * 4;  // %4 == 0
      const int j = gbase >> 2;
      const int b = n0 + nt * 16 + lrow;
      const float4 bv = *(const float4*)(S.bias + gbase);
      const float ig = sigf(acc[mt][nt][0] + bv.x);
      const float fg = sigf(acc[mt][nt][1] + bv.y);
      const float gg = tanhf(acc[mt][nt][2] + bv.z);
      const float og = sigf(acc[mt][nt][3] + bv.w);
      const int idx = j * 256 + b;
      const float cn = fg * S.c[idx] + ig * gg;
      const float hn = og * tanhf(cn);
      S.c[idx] = cn;
      unsigned short hh, hl;
      splitf(hn, hh, hl);
      const int jl = w * 8 + mt * 4 + (lane >> 4);   // 0..31
      const int bl = nt * 16 + lrow;                 // 0..63
      tH[bl * 34 + jl] = hh;
      tL[bl * 34 + jl] = hl;
    }
  __syncthreads();

  // ---- cooperative h store: [b][j] split, 8 ushorts per thread per buffer
  {
    const int row = t >> 2, seg = t & 3;
    const int j0 = m0 >> 2;
    unsigned short vh[8], vl[8];
#pragma unroll
    for (int q = 0; q < 8; ++q) {
      vh[q] = tH[row * 34 + seg * 8 + q];
      vl[q] = tL[row * 34 + seg * 8 + q];
    }
    size_t o = (size_t)(n0 + row) * 256 + j0 + seg * 8;
    *(s8v*)(S.oH + o) = *(const s8v*)vh;
    *(s8v*)(S.oL + o) = *(const s8v*)vl;
    if (S.h3H) {
      size_t o3 = (size_t)(S.h3off + n0 + row) * 256 + j0 + seg * 8;
      *(s8v*)(S.h3H + o3) = *(const s8v*)vh;
      *(s8v*)(S.h3L + o3) = *(const s8v*)vl;
    }
  }
}

// ---------------------------------------------------------------------------

extern "C" void kernel_launch(void* const* d_in, const int* in_sizes, int n_in,
                              void* d_out, int out_size, void* d_ws, size_t ws_size,
                              hipStream_t stream)
{
  const float* x_in  = (const float*)d_in[0];
  const float* w_en1 = (const float*)d_in[1];
  const float* b_en1 = (const float*)d_in[2];
  const float* w_en2 = (const float*)d_in[3];
  const float* b_en2 = (const float*)d_in[4];
  const float* cw[6][4];
  for (int i = 0; i < 6; ++i)
    for (int j = 0; j < 4; ++j) cw[i][j] = (const float*)d_in[5 + i * 4 + j];
  const float* w_de1 = (const float*)d_in[29];
  const float* b_de1 = (const float*)d_in[30];
  const float* w_de2 = (const float*)d_in[31];
  const float* b_de2 = (const float*)d_in[32];
  float* out = (float*)d_out;

  // ---- workspace layout (~93 MB, no aliasing) ----
  float* fs = (float*)d_ws;
  float* bP = fs;                          // 6 * 1024
  float* cb = bP + 6 * 1024;               // 6 * 65536
  unsigned short* us = (unsigned short*)(cb + 6 * 65536);
  unsigned short* hbH   = us;              us += 12 * 65536;
  unsigned short* hbL   = us;              us += 12 * 65536;
  unsigned short* WcatH = us;              us += 6 * 524288;
  unsigned short* WcatL = us;              us += 6 * 524288;
  unsigned short* WEN1H = us;              us += 4194304;
  unsigned short* WEN1L = us;              us += 4194304;
  unsigned short* WEN2H = us;              us += 262144;
  unsigned short* WEN2L = us;              us += 262144;
  unsigned short* WDE1H = us;              us += 262144;
  unsigned short* WDE1L = us;              us += 262144;
  unsigned short* WDE2H = us;              us += 4194304;
  unsigned short* WDE2L = us;              us += 4194304;
  unsigned short* Z1H   = us;              us += 5242880;
  unsigned short* Z1L   = us;              us += 5242880;
  unsigned short* Z2H   = us;              us += 1310720;
  unsigned short* Z2L   = us;              us += 1310720;
  unsigned short* H3H   = us;              us += 655360;
  unsigned short* H3L   = us;              us += 655360;
  unsigned short* Y1H   = us;              us += 2621440;
  unsigned short* Y1L   = us;              us += 2621440;

  // ---- prep: fused packing + fused weight splits + state zero ----
  PrepArgs pa;
  for (int i = 0; i < 6; ++i) {
    pa.wih[i] = cw[i][0]; pa.whh[i] = cw[i][1];
    pa.bih[i] = cw[i][2]; pa.bhh[i] = cw[i][3];
  }
  pa.WcatH = WcatH; pa.WcatL = WcatL; pa.bP = bP;
  prep_cat6<<<dim3(256, 6), 256, 0, stream>>>(pa);

  WsplitArgs wa;
  wa.W[0] = w_en1; wa.WH[0] = WEN1H; wa.WL[0] = WEN1L;
  wa.W[1] = w_en2; wa.WH[1] = WEN2H; wa.WL[1] = WEN2L;
  wa.W[2] = w_de1; wa.WH[2] = WDE1H; wa.WL[2] = WDE1L;
  wa.W[3] = w_de2; wa.WH[3] = WDE2H; wa.WL[3] = WDE2L;
  wsplit4<<<8704, 256, 0, stream>>>(wa);
  // zero c (f32) + h split buffers (bf16 0 == 0x0000), contiguous region
  hipMemsetAsync(cb, 0, (size_t)6 * 65536 * 4 + (size_t)24 * 65536 * 2, stream);

  // ---- encoder feedforward (all MFMA; z2 emitted split, no transpose) ----
  gemm_sf<1><<<dim3(40, 16), 256, 0, stream>>>(
      x_in, WEN1H, WEN1L, b_en1, nullptr, Z1H, Z1L, 5120, 1024, 4096, 1);
  gemm_bb<1><<<dim3(40, 4), 256, 0, stream>>>(
      Z1H, Z1L, WEN2H, WEN2L, b_en2, nullptr, Z2H, Z2L, 5120, 256, 1024, 1);

  // ---- recurrence: layer-pipelined MFMA cell launches ----
  int pp[6] = {0, 0, 0, 0, 0, 0};
  auto HH = [&](int l, int p) { return hbH + (size_t)(l * 2 + p) * 65536; };
  auto HL = [&](int l, int p) { return hbL + (size_t)(l * 2 + p) * 65536; };
  auto CBf = [&](int l) { return cb + (size_t)l * 65536; };
  auto WCH = [&](int l) { return WcatH + (size_t)l * 524288; };
  auto WCL = [&](int l) { return WcatL + (size_t)l * 524288; };
  auto BB = [&](int l) { return bP + (size_t)l * 1024; };

  for (int s = 0; s <= 21; ++s) {
    CArgs a; int n = 0; int tog[3]; int nt = 0;
    if (s < 20) {
      a.s[n++] = {WCH(0), WCL(0), BB(0),
                  Z2H + (size_t)s * 65536, Z2L + (size_t)s * 65536,
                  HH(0, pp[0]), HL(0, pp[0]), CBf(0),
                  HH(0, pp[0] ^ 1), HL(0, pp[0] ^ 1),
                  nullptr, nullptr, 0, 512};
      tog[nt++] = 0;
    }
    if (s >= 1 && s <= 20) {
      a.s[n++] = {WCH(1), WCL(1), BB(1),
                  HH(0, pp[0]), HL(0, pp[0]),
                  HH(1, pp[1]), HL(1, pp[1]), CBf(1),
                  HH(1, pp[1] ^ 1), HL(1, pp[1] ^ 1),
                  nullptr, nullptr, 0, 512};
      tog[nt++] = 1;
    }
    if (s >= 2) {
      a.s[n++] = {WCH(2), WCL(2), BB(2),
                  HH(1, pp[1]), HL(1, pp[1]),
                  HH(2, pp[2]), HL(2, pp[2]), CBf(2),
                  HH(2, pp[2] ^ 1), HL(2, pp[2] ^ 1),
                  nullptr, nullptr, 0, 512};
      tog[nt++] = 2;
    }
    cell_mfma<<<n * 32, 256, 0, stream>>>(a);
    for (int i = 0; i < nt; ++i) pp[tog[i]] ^= 1;
  }

  for (int s = 0; s <= 11; ++s) {
    CArgs a; int n = 0; int tog[3]; int nt = 0;
    if (s < 10) {
      const unsigned short* h1H = (s == 0) ? HH(2, pp[2]) : HH(3, pp[3]);
      const unsigned short* h1L = (s == 0) ? HL(2, pp[2]) : HL(3, pp[3]);
      a.s[n++] = {WCH(3), WCL(3), BB(3),
                  nullptr, nullptr,
                  h1H, h1L, CBf(3),
                  HH(3, pp[3] ^ 1), HL(3, pp[3] ^ 1),
                  nullptr, nullptr, 0, 256};
      tog[nt++] = 3;
    }
    if (s >= 1 && s <= 10) {
      a.s[n++] = {WCH(4), WCL(4), BB(4),
                  HH(3, pp[3]), HL(3, pp[3]),
                  HH(4, pp[4]), HL(4, pp[4]), CBf(4),
                  HH(4, pp[4] ^ 1), HL(4, pp[4] ^ 1),
                  nullptr, nullptr, 0, 512};
      tog[nt++] = 4;
    }
    if (s >= 2) {
      a.s[n++] = {WCH(5), WCL(5), BB(5),
                  HH(4, pp[4]), HL(4, pp[4]),
                  HH(5, pp[5]), HL(5, pp[5]), CBf(5),
                  HH(5, pp[5] ^ 1), HL(5, pp[5] ^ 1),
                  H3H, H3L, (s - 2) * 256, 512};
      tog[nt++] = 5;
    }
    cell_mfma<<<n * 32, 256, 0, stream>>>(a);
    for (int i = 0; i < nt; ++i) pp[tog[i]] ^= 1;
  }

  // ---- decoder output FCs (H3 already split, no transpose) ----
  gemm_bb<1><<<dim3(20, 16), 256, 0, stream>>>(
      H3H, H3L, WDE1H, WDE1L, b_de1, nullptr, Y1H, Y1L, 2560, 1024, 256, 1);
  gemm_bb<0><<<dim3(20, 64), 256, 0, stream>>>(
      Y1H, Y1L, WDE2H, WDE2L, b_de2, out, nullptr, nullptr, 2560, 4096, 1024, 2);

  (void)in_sizes; (void)n_in; (void)out_size; (void)ws_size;
}

// Round 19
// 839.788 us; speedup vs baseline: 1.1114x; 1.1114x over previous
//
#include <hip/hip_runtime.h>
#include <math.h>

static __device__ __forceinline__ float sigf(float v) { return 1.0f / (1.0f + expf(-v)); }

using s8v = __attribute__((ext_vector_type(8))) short;   // 8 bf16 (4 VGPR)
using f4v = __attribute__((ext_vector_type(4))) float;   // MFMA acc

static __device__ __forceinline__ void splitf(float f, unsigned short& h, unsigned short& l) {
  unsigned u = __float_as_uint(f);
  unsigned short hb = (unsigned short)((u + 0x7FFFu + ((u >> 16) & 1u)) >> 16);
  float hf = __uint_as_float(((unsigned)hb) << 16);
  float lf = f - hf;
  unsigned ul = __float_as_uint(lf);
  unsigned short lb = (unsigned short)((ul + 0x7FFFu + ((ul >> 16) & 1u)) >> 16);
  h = hb; l = lb;
}

// Fast float4 -> packed bf16 hi/lo via HW v_cvt_pk_bf16_f32 (RTNE).
static __device__ __forceinline__ void splitf4(float4 a, uint2& hOut, uint2& lOut) {
  unsigned hxy, hzw;
  asm("v_cvt_pk_bf16_f32 %0, %1, %2" : "=v"(hxy) : "v"(a.x), "v"(a.y));
  asm("v_cvt_pk_bf16_f32 %0, %1, %2" : "=v"(hzw) : "v"(a.z), "v"(a.w));
  float hx = __uint_as_float(hxy << 16);
  float hy = __uint_as_float(hxy & 0xFFFF0000u);
  float hz = __uint_as_float(hzw << 16);
  float hw = __uint_as_float(hzw & 0xFFFF0000u);
  unsigned lxy, lzw;
  asm("v_cvt_pk_bf16_f32 %0, %1, %2" : "=v"(lxy) : "v"(a.x - hx), "v"(a.y - hy));
  asm("v_cvt_pk_bf16_f32 %0, %1, %2" : "=v"(lzw) : "v"(a.z - hz), "v"(a.w - hw));
  hOut.x = hxy; hOut.y = hzw;
  lOut.x = lxy; lOut.y = lzw;
}

// ---------------------------------------------------------------------------
// Fused weight split: 4 segments (en1, en2, de1, de2) in one launch.
// Segment sizes in f4: 1048576, 65536, 65536, 1048576 -> 4096/256/256/4096 blks.
// ---------------------------------------------------------------------------
struct WsplitArgs {
  const float* W[4];
  unsigned short* WH[4];
  unsigned short* WL[4];
};
__global__ __launch_bounds__(256) void wsplit4(WsplitArgs a)
{
  int blk = blockIdx.x;
  int seg, base;
  if (blk < 4096)      { seg = 0; base = blk; }
  else if (blk < 4352) { seg = 1; base = blk - 4096; }
  else if (blk < 4608) { seg = 2; base = blk - 4352; }
  else                 { seg = 3; base = blk - 4608; }
  int i = base * 256 + threadIdx.x;
  float4 v = ((const float4*)a.W[seg])[i];
  ushort4 h, l;
  splitf(v.x, h.x, l.x); splitf(v.y, h.y, l.y);
  splitf(v.z, h.z, l.z); splitf(v.w, h.w, l.w);
  ((ushort4*)a.WH[seg])[i] = h;
  ((ushort4*)a.WL[seg])[i] = l;
}

// ---------------------------------------------------------------------------
// MFMA GEMM, A fp32 split on the fly (HW cvt_pk), W pre-split. (fc_en1)
// Tile 128(M) x 64(N), BK=32, 4 waves.
// OSPLIT=1: write bf16 hi/lo pair (act applied first). act: 1=relu, 2=tanh.
// ---------------------------------------------------------------------------
template <int OSPLIT>
__global__ __launch_bounds__(256) void gemm_sf(
    const float* __restrict__ A,
    const unsigned short* __restrict__ WH, const unsigned short* __restrict__ WL,
    const float* __restrict__ bias, float* __restrict__ C,
    unsigned short* __restrict__ OH, unsigned short* __restrict__ OL,
    int M, int N, int K, int act)
{
  __shared__ unsigned short AsH[128 * 40];
  __shared__ unsigned short AsL[128 * 40];
  __shared__ unsigned short WsH[64 * 40];
  __shared__ unsigned short WsL[64 * 40];

  const int t = threadIdx.x;
  const int w = t >> 6, lane = t & 63;
  const int lrow = lane & 15, lk = (lane >> 4) * 8;
  const int m0 = blockIdx.x * 128, n0 = blockIdx.y * 64;

  f4v acc[2][4];
#pragma unroll
  for (int i = 0; i < 2; ++i)
#pragma unroll
    for (int j = 0; j < 4; ++j) acc[i][j] = (f4v){0.f, 0.f, 0.f, 0.f};

  for (int k0 = 0; k0 < K; k0 += 32) {
#pragma unroll
    for (int i = 0; i < 4; ++i) {
      int v = i * 256 + t;
      int row = v >> 3, kq = (v & 7) << 2;   // kq in {0,4,...,28}: 8B-aligned
      float4 a = *(const float4*)(A + (size_t)(m0 + row) * K + k0 + kq);
      uint2 h2, l2;
      splitf4(a, h2, l2);
      *(uint2*)&AsH[row * 40 + kq] = h2;
      *(uint2*)&AsL[row * 40 + kq] = l2;
    }
    {
      int row = t >> 2, q = (t & 3) * 8;
      *(s8v*)&WsH[row * 40 + q] = *(const s8v*)(WH + (size_t)(n0 + row) * K + k0 + q);
      *(s8v*)&WsL[row * 40 + q] = *(const s8v*)(WL + (size_t)(n0 + row) * K + k0 + q);
    }
    __syncthreads();

    s8v aH[2], aL[2], bH[4], bL[4];
#pragma unroll
    for (int mt = 0; mt < 2; ++mt) {
      int r = (w * 32 + mt * 16 + lrow) * 40 + lk;
      aH[mt] = *(const s8v*)&AsH[r];
      aL[mt] = *(const s8v*)&AsL[r];
    }
#pragma unroll
    for (int nt = 0; nt < 4; ++nt) {
      int r = (nt * 16 + lrow) * 40 + lk;
      bH[nt] = *(const s8v*)&WsH[r];
      bL[nt] = *(const s8v*)&WsL[r];
    }
#pragma unroll
    for (int mt = 0; mt < 2; ++mt)
#pragma unroll
      for (int nt = 0; nt < 4; ++nt) {
        acc[mt][nt] = __builtin_amdgcn_mfma_f32_16x16x32_bf16(aH[mt], bH[nt], acc[mt][nt], 0, 0, 0);
        acc[mt][nt] = __builtin_amdgcn_mfma_f32_16x16x32_bf16(aH[mt], bL[nt], acc[mt][nt], 0, 0, 0);
        acc[mt][nt] = __builtin_amdgcn_mfma_f32_16x16x32_bf16(aL[mt], bH[nt], acc[mt][nt], 0, 0, 0);
      }
    __syncthreads();
  }

#pragma unroll
  for (int mt = 0; mt < 2; ++mt)
#pragma unroll
    for (int nt = 0; nt < 4; ++nt) {
      int gcol = n0 + nt * 16 + lrow;
      float bv = bias[gcol];
#pragma unroll
      for (int r = 0; r < 4; ++r) {
        int grow = m0 + w * 32 + mt * 16 + (lane >> 4) * 4 + r;
        float v = acc[mt][nt][r] + bv;
        if (act == 1) v = fmaxf(v, 0.f);
        else if (act == 2) v = tanhf(v);
        if (OSPLIT) {
          unsigned short h, l;
          splitf(v, h, l);
          OH[(size_t)grow * N + gcol] = h;
          OL[(size_t)grow * N + gcol] = l;
        } else {
          C[(size_t)grow * N + gcol] = v;
        }
      }
    }
}

// ---------------------------------------------------------------------------
// MFMA GEMM, A AND W pre-split bf16. Tile 128x64, BK=32.
// ---------------------------------------------------------------------------
template <int OSPLIT>
__global__ __launch_bounds__(256) void gemm_bb(
    const unsigned short* __restrict__ AH, const unsigned short* __restrict__ AL,
    const unsigned short* __restrict__ WH, const unsigned short* __restrict__ WL,
    const float* __restrict__ bias, float* __restrict__ C,
    unsigned short* __restrict__ OH, unsigned short* __restrict__ OL,
    int M, int N, int K, int act)
{
  __shared__ unsigned short AsH[128 * 40];
  __shared__ unsigned short AsL[128 * 40];
  __shared__ unsigned short WsH[64 * 40];
  __shared__ unsigned short WsL[64 * 40];

  const int t = threadIdx.x;
  const int w = t >> 6, lane = t & 63;
  const int lrow = lane & 15, lk = (lane >> 4) * 8;
  const int m0 = blockIdx.x * 128, n0 = blockIdx.y * 64;

  f4v acc[2][4];
#pragma unroll
  for (int i = 0; i < 2; ++i)
#pragma unroll
    for (int j = 0; j < 4; ++j) acc[i][j] = (f4v){0.f, 0.f, 0.f, 0.f};

  for (int k0 = 0; k0 < K; k0 += 32) {
#pragma unroll
    for (int i = 0; i < 2; ++i) {
      int v = i * 256 + t;
      int row = v >> 2, q = (v & 3) * 8;
      *(s8v*)&AsH[row * 40 + q] = *(const s8v*)(AH + (size_t)(m0 + row) * K + k0 + q);
      *(s8v*)&AsL[row * 40 + q] = *(const s8v*)(AL + (size_t)(m0 + row) * K + k0 + q);
    }
    {
      int row = t >> 2, q = (t & 3) * 8;
      *(s8v*)&WsH[row * 40 + q] = *(const s8v*)(WH + (size_t)(n0 + row) * K + k0 + q);
      *(s8v*)&WsL[row * 40 + q] = *(const s8v*)(WL + (size_t)(n0 + row) * K + k0 + q);
    }
    __syncthreads();

    s8v aH[2], aL[2], bH[4], bL[4];
#pragma unroll
    for (int mt = 0; mt < 2; ++mt) {
      int r = (w * 32 + mt * 16 + lrow) * 40 + lk;
      aH[mt] = *(const s8v*)&AsH[r];
      aL[mt] = *(const s8v*)&AsL[r];
    }
#pragma unroll
    for (int nt = 0; nt < 4; ++nt) {
      int r = (nt * 16 + lrow) * 40 + lk;
      bH[nt] = *(const s8v*)&WsH[r];
      bL[nt] = *(const s8v*)&WsL[r];
    }
#pragma unroll
    for (int mt = 0; mt < 2; ++mt)
#pragma unroll
      for (int nt = 0; nt < 4; ++nt) {
        acc[mt][nt] = __builtin_amdgcn_mfma_f32_16x16x32_bf16(aH[mt], bH[nt], acc[mt][nt], 0, 0, 0);
        acc[mt][nt] = __builtin_amdgcn_mfma_f32_16x16x32_bf16(aH[mt], bL[nt], acc[mt][nt], 0, 0, 0);
        acc[mt][nt] = __builtin_amdgcn_mfma_f32_16x16x32_bf16(aL[mt], bH[nt], acc[mt][nt], 0, 0, 0);
      }
    __syncthreads();
  }

#pragma unroll
  for (int mt = 0; mt < 2; ++mt)
#pragma unroll
    for (int nt = 0; nt < 4; ++nt) {
      int gcol = n0 + nt * 16 + lrow;
      float bv = bias[gcol];
#pragma unroll
      for (int r = 0; r < 4; ++r) {
        int grow = m0 + w * 32 + mt * 16 + (lane >> 4) * 4 + r;
        float v = acc[mt][nt][r] + bv;
        if (act == 1) v = fmaxf(v, 0.f);
        else if (act == 2) v = tanhf(v);
        if (OSPLIT) {
          unsigned short h, l;
          splitf(v, h, l);
          OH[(size_t)grow * N + gcol] = h;
          OL[(size_t)grow * N + gcol] = l;
        } else {
          C[(size_t)grow * N + gcol] = v;
        }
      }
    }
}

// ---------------------------------------------------------------------------
// Fused cell-weight packing: all 6 layers in one launch. grid (256, 6).
// ---------------------------------------------------------------------------
struct PrepArgs {
  const float* wih[6];
  const float* whh[6];
  const float* bih[6];
  const float* bhh[6];
  float* wihP;   // [6][262144]
  float* whhP;   // [6][262144]
  float* bP;     // [6][1024]
};
__global__ __launch_bounds__(256) void prep_pack6(PrepArgs a)
{
  const int l = blockIdx.y;
  const int j = blockIdx.x, k = threadIdx.x;
  const float* wih = a.wih[l];
  const float* whh = a.whh[l];
  float* wihP = a.wihP + (size_t)l * 262144;
  float* whhP = a.whhP + (size_t)l * 262144;
  float4 v, c;
  v.x = wih[(0 * 256 + j) * 256 + k];
  v.y = wih[(1 * 256 + j) * 256 + k];
  v.z = wih[(2 * 256 + j) * 256 + k];
  v.w = wih[(3 * 256 + j) * 256 + k];
  *(float4*)&wihP[((size_t)j * 256 + k) * 4] = v;
  c.x = whh[(0 * 256 + j) * 256 + k];
  c.y = whh[(1 * 256 + j) * 256 + k];
  c.z = whh[(2 * 256 + j) * 256 + k];
  c.w = whh[(3 * 256 + j) * 256 + k];
  *(float4*)&whhP[((size_t)j * 256 + k) * 4] = c;
  if (k < 4)
    a.bP[l * 1024 + j * 4 + k] = a.bih[l][k * 256 + j] + a.bhh[l][k * 256 + j];
}

// ---------------------------------------------------------------------------
// Per-slab 256x256 transpose (f32): out[t][c][r] = in[t][r][c].
// ---------------------------------------------------------------------------
__global__ __launch_bounds__(256) void transpose256(
    const float* __restrict__ in, float* __restrict__ out)
{
  const int t = blockIdx.x, c4 = blockIdx.y;
  const int r = threadIdx.x;
  float4 v = *(const float4*)(in + ((size_t)t * 256 + r) * 256 + c4 * 4);
  float* op = out + (size_t)t * 65536 + (size_t)(c4 * 4) * 256 + r;
  op[0]   = v.x;
  op[256] = v.y;
  op[512] = v.z;
  op[768] = v.w;
}

// ---------------------------------------------------------------------------
// Transpose + bf16-split: outH/L[t][c][r] = split(in[t][r][c]).
// ---------------------------------------------------------------------------
__global__ __launch_bounds__(256) void transpose256s(
    const float* __restrict__ in, unsigned short* __restrict__ outH,
    unsigned short* __restrict__ outL)
{
  const int t = blockIdx.x, c4 = blockIdx.y;
  const int r = threadIdx.x;
  float4 v = *(const float4*)(in + ((size_t)t * 256 + r) * 256 + c4 * 4);
  ushort4 h, l;
  splitf(v.x, h.x, l.x); splitf(v.y, h.y, l.y);
  splitf(v.z, h.z, l.z); splitf(v.w, h.w, l.w);
  size_t o = (size_t)t * 65536 + (size_t)(c4 * 4) * 256 + r;
  outH[o] = h.x; outH[o + 256] = h.y; outH[o + 512] = h.z; outH[o + 768] = h.w;
  outL[o] = l.x; outL[o + 256] = l.y; outL[o + 512] = l.z; outL[o + 768] = l.w;
}

// ---------------------------------------------------------------------------
// Multi-slot LSTM cell kernel with k-split=2 (scalar-path preserving).
// Slot = blockIdx.x>>8; inner 256 blocks = bg(4)-major x jg(64).
// Block 512 thr = 8 waves: wave = kh(2) x jwv(4). kh and jw routed through
// readfirstlane -> SGPR base pointers, compile-time loop bounds.
// ---------------------------------------------------------------------------
struct CellSlot {
  const float* x;     // [256][256] (k,b) or null
  const float* wih;   // [j][256][4]
  const float* whh;   // [j][256][4]
  const float* bias;  // [j][4]
  const float* hin;   // [256][256] (k,b)
  float* c;           // [256][256] (j,b) in-place
  float* hout;        // [256][256] (j,b)
  float* hcopy;       // optional
  int hasx;
};
struct CellArgs { CellSlot s[3]; };

__global__ __launch_bounds__(512) void cell_multi(CellArgs args)
{
  __shared__ float part[4][64][4];  // [jwv][lane][gate]
  const CellSlot S = args.s[blockIdx.x >> 8];
  const int inner = blockIdx.x & 255;
  const int jg = inner & 63, bg = inner >> 6;
  const int t = threadIdx.x;
  const int lane = t & 63;
  const int wave = t >> 6;
  const int jwv = wave & 3;
  const int kh = __builtin_amdgcn_readfirstlane(wave >> 2);   // SGPR
  const int b = bg * 64 + lane;

  const int jw = __builtin_amdgcn_readfirstlane(jg * 4 + jwv); // SGPR
  const float4* wh = (const float4*)(S.whh + (size_t)jw * 1024) + kh * 128;
  const float4* wi = (const float4*)(S.wih + (size_t)jw * 1024) + kh * 128;
  const float* hcol = S.hin + (size_t)kh * 128 * 256 + b;

  float4 acc;
  if (kh == 0) acc = *(const float4*)(S.bias + jw * 4);
  else         acc = (float4){0.f, 0.f, 0.f, 0.f};

  if (S.hasx) {
    const float* xcol = S.x + (size_t)kh * 128 * 256 + b;
#pragma unroll 8
    for (int k = 0; k < 128; ++k) {
      const float hv = hcol[k * 256];
      const float4 wv = wh[k];
      acc.x = fmaf(hv, wv.x, acc.x);
      acc.y = fmaf(hv, wv.y, acc.y);
      acc.z = fmaf(hv, wv.z, acc.z);
      acc.w = fmaf(hv, wv.w, acc.w);
      const float xv = xcol[k * 256];
      const float4 vv = wi[k];
      acc.x = fmaf(xv, vv.x, acc.x);
      acc.y = fmaf(xv, vv.y, acc.y);
      acc.z = fmaf(xv, vv.z, acc.z);
      acc.w = fmaf(xv, vv.w, acc.w);
    }
  } else {
#pragma unroll 8
    for (int k = 0; k < 128; ++k) {
      const float hv = hcol[k * 256];
      const float4 wv = wh[k];
      acc.x = fmaf(hv, wv.x, acc.x);
      acc.y = fmaf(hv, wv.y, acc.y);
      acc.z = fmaf(hv, wv.z, acc.z);
      acc.w = fmaf(hv, wv.w, acc.w);
    }
  }

  if (kh == 1) *(float4*)&part[jwv][lane][0] = acc;
  __syncthreads();
  if (kh == 0) {
    const float4 p = *(const float4*)&part[jwv][lane][0];
    acc.x += p.x; acc.y += p.y; acc.z += p.z; acc.w += p.w;

    const int idx = jw * 256 + b;
    const float cold = S.c[idx];
    const float ig = sigf(acc.x), fg = sigf(acc.y);
    const float gg = tanhf(acc.z), og = sigf(acc.w);
    const float cn = fg * cold + ig * gg;
    const float hn = og * tanhf(cn);
    S.c[idx] = cn;
    S.hout[idx] = hn;
    if (S.hcopy) S.hcopy[idx] = hn;
  }
}

// ---------------------------------------------------------------------------

extern "C" void kernel_launch(void* const* d_in, const int* in_sizes, int n_in,
                              void* d_out, int out_size, void* d_ws, size_t ws_size,
                              hipStream_t stream)
{
  const float* x_in  = (const float*)d_in[0];
  const float* w_en1 = (const float*)d_in[1];
  const float* b_en1 = (const float*)d_in[2];
  const float* w_en2 = (const float*)d_in[3];
  const float* b_en2 = (const float*)d_in[4];
  const float* cw[6][4];
  for (int i = 0; i < 6; ++i)
    for (int j = 0; j < 4; ++j) cw[i][j] = (const float*)d_in[5 + i * 4 + j];
  const float* w_de1 = (const float*)d_in[29];
  const float* b_de1 = (const float*)d_in[30];
  const float* w_de2 = (const float*)d_in[31];
  const float* b_de2 = (const float*)d_in[32];
  float* out = (float*)d_out;

  // ---- workspace layout (round-13 structure, ~87 MB) ----
  float* fs   = (float*)d_ws;
  float* wihP = fs;                        // 6 * 262144 f
  float* whhP = wihP + 6 * 262144;         // 6 * 262144 f
  float* bP   = whhP + 6 * 262144;         // 6 * 1024 f
  float* hb   = bP + 6 * 1024;             // 12 * 65536 f
  float* cb   = hb + 12 * 65536;           // 6 * 65536 f
  float* H3T  = cb + 6 * 65536;            // 10 * 65536 f
  float* z2   = H3T + 10 * 65536;          // 1,310,720 f
  float* z2T  = z2 + 1310720;              // 1,310,720 f
  unsigned short* us = (unsigned short*)(z2T + 1310720);
  unsigned short* WEN1H = us;              us += 4194304;
  unsigned short* WEN1L = us;              us += 4194304;
  unsigned short* WEN2H = us;              us += 262144;
  unsigned short* WEN2L = us;              us += 262144;
  unsigned short* WDE1H = us;              us += 262144;
  unsigned short* WDE1L = us;              us += 262144;
  unsigned short* WDE2H = us;              us += 4194304;
  unsigned short* WDE2L = us;              us += 4194304;
  unsigned short* Z1H   = us;              us += 5242880;
  unsigned short* Z1L   = us;              us += 5242880;
  // Y1/H3 alias the (dead-by-then) Z1 region:
  unsigned short* H3H = Z1H;
  unsigned short* H3L = Z1H + 655360;
  unsigned short* Y1H = Z1H + 1310720;
  unsigned short* Y1L = Z1H + 1310720 + 2621440;

  // ---- prep: fused packing + fused weight splits + state zero ----
  PrepArgs pa;
  for (int i = 0; i < 6; ++i) {
    pa.wih[i] = cw[i][0]; pa.whh[i] = cw[i][1];
    pa.bih[i] = cw[i][2]; pa.bhh[i] = cw[i][3];
  }
  pa.wihP = wihP; pa.whhP = whhP; pa.bP = bP;
  prep_pack6<<<dim3(256, 6), 256, 0, stream>>>(pa);

  WsplitArgs wa;
  wa.W[0] = w_en1; wa.WH[0] = WEN1H; wa.WL[0] = WEN1L;
  wa.W[1] = w_en2; wa.WH[1] = WEN2H; wa.WL[1] = WEN2L;
  wa.W[2] = w_de1; wa.WH[2] = WDE1H; wa.WL[2] = WDE1L;
  wa.W[3] = w_de2; wa.WH[3] = WDE2H; wa.WL[3] = WDE2L;
  wsplit4<<<8704, 256, 0, stream>>>(wa);
  hipMemsetAsync(hb, 0, (size_t)18 * 65536 * sizeof(float), stream);

  // ---- encoder feedforward (all MFMA) ----
  gemm_sf<1><<<dim3(40, 16), 256, 0, stream>>>(
      x_in, WEN1H, WEN1L, b_en1, nullptr, Z1H, Z1L, 5120, 1024, 4096, 1);
  gemm_bb<0><<<dim3(40, 4), 256, 0, stream>>>(
      Z1H, Z1L, WEN2H, WEN2L, b_en2, z2, nullptr, nullptr, 5120, 256, 1024, 1);
  transpose256<<<dim3(20, 64), 256, 0, stream>>>(z2, z2T);

  // ---- recurrence: layer-pipelined cell launches (k-split=2 blocks) ----
  int pp[6] = {0, 0, 0, 0, 0, 0};
  auto HBuf = [&](int l, int p) { return hb + (size_t)(l * 2 + p) * 65536; };
  auto CBuf = [&](int l) { return cb + (size_t)l * 65536; };
  auto WI = [&](int l) { return wihP + (size_t)l * 262144; };
  auto WHp = [&](int l) { return whhP + (size_t)l * 262144; };
  auto BB = [&](int l) { return bP + (size_t)l * 1024; };

  for (int s = 0; s <= 21; ++s) {
    CellArgs a; int n = 0; int tog[3]; int nt = 0;
    if (s < 20) {
      a.s[n++] = {z2T + (size_t)s * 65536, WI(0), WHp(0), BB(0),
                  HBuf(0, pp[0]), CBuf(0), HBuf(0, pp[0] ^ 1), nullptr, 1};
      tog[nt++] = 0;
    }
    if (s >= 1 && s <= 20) {
      a.s[n++] = {HBuf(0, pp[0]), WI(1), WHp(1), BB(1),
                  HBuf(1, pp[1]), CBuf(1), HBuf(1, pp[1] ^ 1), nullptr, 1};
      tog[nt++] = 1;
    }
    if (s >= 2) {
      a.s[n++] = {HBuf(1, pp[1]), WI(2), WHp(2), BB(2),
                  HBuf(2, pp[2]), CBuf(2), HBuf(2, pp[2] ^ 1), nullptr, 1};
      tog[nt++] = 2;
    }
    cell_multi<<<n * 256, 512, 0, stream>>>(a);
    for (int i = 0; i < nt; ++i) pp[tog[i]] ^= 1;
  }

  for (int s = 0; s <= 11; ++s) {
    CellArgs a; int n = 0; int tog[3]; int nt = 0;
    if (s < 10) {
      const float* h1in = (s == 0) ? HBuf(2, pp[2]) : HBuf(3, pp[3]);
      a.s[n++] = {nullptr, WI(3), WHp(3), BB(3),
                  h1in, CBuf(3), HBuf(3, pp[3] ^ 1), nullptr, 0};
      tog[nt++] = 3;
    }
    if (s >= 1 && s <= 10) {
      a.s[n++] = {HBuf(3, pp[3]), WI(4), WHp(4), BB(4),
                  HBuf(4, pp[4]), CBuf(4), HBuf(4, pp[4] ^ 1), nullptr, 1};
      tog[nt++] = 4;
    }
    if (s >= 2) {
      a.s[n++] = {HBuf(4, pp[4]), WI(5), WHp(5), BB(5),
                  HBuf(5, pp[5]), CBuf(5), HBuf(5, pp[5] ^ 1),
                  H3T + (size_t)(s - 2) * 65536, 1};
      tog[nt++] = 5;
    }
    cell_multi<<<n * 256, 512, 0, stream>>>(a);
    for (int i = 0; i < nt; ++i) pp[tog[i]] ^= 1;
  }

  // ---- decoder output FCs (all MFMA) ----
  transpose256s<<<dim3(10, 64), 256, 0, stream>>>(H3T, H3H, H3L);  // [s][j][b]->[s][b][j]
  gemm_bb<1><<<dim3(20, 16), 256, 0, stream>>>(
      H3H, H3L, WDE1H, WDE1L, b_de1, nullptr, Y1H, Y1L, 2560, 1024, 256, 1);
  gemm_bb<0><<<dim3(20, 64), 256, 0, stream>>>(
      Y1H, Y1L, WDE2H, WDE2L, b_de2, out, nullptr, nullptr, 2560, 4096, 1024, 2);

  (void)in_sizes; (void)n_in; (void)out_size; (void)ws_size;
}